// Round 2
// baseline (143.978 us; speedup 1.0000x reference)
//
#include <hip/hip_runtime.h>

// Problem constants (from reference)
#define NNZ_TOT    2097152
#define N_CELLS    4096
#define N_GIN      20000     // input genes
#define N_PRE      30000     // pretrained table rows
#define NUM_HID    128
#define HID_HALF   64

// Workspace: g_arr [NNZ] int, ebf0/ebf1 [N_PRE,64] bf16 halves, rp [N_CELLS+1]
#define GA_OFF     0
#define GA_BYTES   ((size_t)NNZ_TOT * 4)                      // 8 MB
#define EBFH_BYTES ((size_t)N_PRE * HID_HALF * 2)             // 3.84 MB each
#define EBF0_OFF   (GA_OFF + GA_BYTES)
#define EBF1_OFF   (EBF0_OFF + EBFH_BYTES)
#define RP_OFF     (EBF1_OFF + EBFH_BYTES)
#define RP_BYTES   ((((size_t)(N_CELLS + 1) * 4) + 255) & ~(size_t)255)
#define WS_NEED    (RP_OFF + RP_BYTES)

// native clang vector type — __builtin_nontemporal_store rejects HIP's
// struct-based float4, accepts ext_vector_type
typedef float vfloat4 __attribute__((ext_vector_type(4)));

__device__ __forceinline__ unsigned short f2bf(float f) {
    union { float f; unsigned u; } c; c.f = f;
    unsigned u = c.u;
    u += 0x7fffu + ((u >> 16) & 1u);    // round-to-nearest-even
    return (unsigned short)(u >> 16);
}

// ---------------------------------------------------------------------------
// P1: fused precompute — blocks [0, NB_GA) do g_arr[i] = gidx[xc[i]];
// blocks [NB_GA, NB_GA+NB_RP) do CSR row pointers (binary search).
// ---------------------------------------------------------------------------
#define NB_GA ((NNZ_TOT + 255) / 256)         // 8192 blocks
#define NB_RP ((N_CELLS + 256) / 256)         // 17 blocks

__global__ __launch_bounds__(256) void precompute_kernel(
    const int* __restrict__ xc, const int* __restrict__ gidx,
    const int* __restrict__ xr, int* __restrict__ g_arr,
    int* __restrict__ rp)
{
    const int b = blockIdx.x;
    if (b < NB_GA) {
        const int i = b * 256 + threadIdx.x;
        if (i < NNZ_TOT) g_arr[i] = gidx[xc[i]];
    } else {
        const int r = (b - NB_GA) * 256 + threadIdx.x;
        if (r <= N_CELLS) {
            int lo = 0, hi = NNZ_TOT;
            while (lo < hi) {
                const int mid = (lo + hi) >> 1;
                if (xr[mid] < r) lo = mid + 1; else hi = mid;
            }
            rp[r] = lo;
        }
    }
}

// ---------------------------------------------------------------------------
// P2: bf16 copy of the embedding table, SPLIT into two half-tables:
// ebf0 = dims [0,64), ebf1 = dims [64,128). Each half is 3.84 MB — below one
// XCD's 4 MB L2 — so a CU group that only touches one half keeps it fully
// L2-resident (the latency term in the MSHR-limit equation).
// ---------------------------------------------------------------------------
__global__ __launch_bounds__(256) void convert_embs_kernel(
    const float* __restrict__ embs, unsigned short* __restrict__ ebf0,
    unsigned short* __restrict__ ebf1)
{
    const int i = blockIdx.x * blockDim.x + threadIdx.x;   // per 4 floats
    const long idx = (long)i * 4;
    if (idx < (long)N_PRE * NUM_HID) {
        const float4 f = *reinterpret_cast<const float4*>(&embs[idx]);
        ushort4 o;
        o.x = f2bf(f.x); o.y = f2bf(f.y); o.z = f2bf(f.z); o.w = f2bf(f.w);
        const int row = (int)(idx >> 7);          // /128
        const int col = (int)(idx & 127);
        unsigned short* __restrict__ dst = (col < HID_HALF) ? ebf0 : ebf1;
        *reinterpret_cast<ushort4*>(&dst[row * HID_HALF + (col & 63)]) = o;
    }
}

// ---------------------------------------------------------------------------
// Main: one wave per (row, hidden-half); halves pinned to XCD groups.
// blockIdx&7 -> XCD (round-robin dispatch heuristic, m09): xcd 0-3 take
// dims [0,64) (ebf0), xcd 4-7 take dims [64,128) (ebf1). Per-XCD gather
// working set = 3.84 MB < 4 MB L2 -> all L1-miss fills served at L2 latency
// instead of ~50% Infinity-Cache fills. Under the measured per-CU
// miss-tracking limit (19 B/cyc/CU ~ MSHRs x latency), cutting avg latency
// is the only remaining lever; structure was already shown insensitive.
// Lane = (oct = lane>>3 picks 1 of 8 consecutive nnz, sub = lane&7 owns
// dims [sub*8, sub*8+8) of the half) -> one global_load_dwordx4 fetches 8
// complete 128-B half-rows, every byte consumed. 64 nnz/iter, 8 gather
// chains. xv/ga streams (read twice now, once per half) are non-temporal
// so they can't evict the L2-resident half-table; gathers stay plain loads
// (R10: nt on gathers was harmful). No atomics, no LDS, no private arrays.
// 8192 waves -> 32 waves/CU (VGPR<=64) = full occupancy.
// ---------------------------------------------------------------------------
__device__ __forceinline__ void fma8(uint4 f, float vv, float4& a0, float4& a1) {
    a0.x = fmaf(vv, __uint_as_float(f.x << 16),         a0.x);
    a0.y = fmaf(vv, __uint_as_float(f.x & 0xffff0000u), a0.y);
    a0.z = fmaf(vv, __uint_as_float(f.y << 16),         a0.z);
    a0.w = fmaf(vv, __uint_as_float(f.y & 0xffff0000u), a0.w);
    a1.x = fmaf(vv, __uint_as_float(f.z << 16),         a1.x);
    a1.y = fmaf(vv, __uint_as_float(f.z & 0xffff0000u), a1.y);
    a1.z = fmaf(vv, __uint_as_float(f.w << 16),         a1.z);
    a1.w = fmaf(vv, __uint_as_float(f.w & 0xffff0000u), a1.w);
}

__global__ __launch_bounds__(256) void omics_half_kernel(
    const float*          __restrict__ xv,    // [NNZ] values
    const int*            __restrict__ ga,    // [NNZ] gene ids (fused)
    const int*            __restrict__ rp,    // [N_CELLS+1]
    const unsigned short* __restrict__ ebf0,  // [N_PRE,64] bf16 dims 0..63
    const unsigned short* __restrict__ ebf1,  // [N_PRE,64] bf16 dims 64..127
    float*                __restrict__ out)   // [N_CELLS,128]
{
    const int blk  = blockIdx.x;              // [0, 2048)
    const int xcd  = blk & 7;
    const int half = xcd >> 2;                // 0: dims[0,64)  1: dims[64,128)
    const int grp  = ((blk >> 3) << 2) | (xcd & 3);   // [0, 1024)
    const int wid  = threadIdx.x >> 6;        // wave in block, 0..3
    const int lane = threadIdx.x & 63;
    const int sub  = lane & 7;
    const int oct  = lane >> 3;
    const int r    = __builtin_amdgcn_readfirstlane((grp << 2) | wid);

    const unsigned short* __restrict__ eb = half ? ebf1 : ebf0;

    const int lo = rp[r];
    const int hi = rp[r + 1];
    const int h8 = sub * 8;                   // bf16 elems within the half

    float4 a0 = make_float4(0.f, 0.f, 0.f, 0.f);
    float4 a1 = make_float4(0.f, 0.f, 0.f, 0.f);
    float4 b0 = make_float4(0.f, 0.f, 0.f, 0.f);
    float4 b1 = make_float4(0.f, 0.f, 0.f, 0.f);

    int i = lo;
    for (; i + 64 <= hi; i += 64) {
        const int i0 = i + oct;
        const int g0 = __builtin_nontemporal_load(ga + i0);
        const int g1 = __builtin_nontemporal_load(ga + i0 + 8);
        const int g2 = __builtin_nontemporal_load(ga + i0 + 16);
        const int g3 = __builtin_nontemporal_load(ga + i0 + 24);
        const int g4 = __builtin_nontemporal_load(ga + i0 + 32);
        const int g5 = __builtin_nontemporal_load(ga + i0 + 40);
        const int g6 = __builtin_nontemporal_load(ga + i0 + 48);
        const int g7 = __builtin_nontemporal_load(ga + i0 + 56);
        const float v0 = __builtin_nontemporal_load(xv + i0);
        const float v1 = __builtin_nontemporal_load(xv + i0 + 8);
        const float v2 = __builtin_nontemporal_load(xv + i0 + 16);
        const float v3 = __builtin_nontemporal_load(xv + i0 + 24);
        const float v4 = __builtin_nontemporal_load(xv + i0 + 32);
        const float v5 = __builtin_nontemporal_load(xv + i0 + 40);
        const float v6 = __builtin_nontemporal_load(xv + i0 + 48);
        const float v7 = __builtin_nontemporal_load(xv + i0 + 56);

        const uint4 f0 = *reinterpret_cast<const uint4*>(&eb[(long)g0 * HID_HALF + h8]);
        const uint4 f1 = *reinterpret_cast<const uint4*>(&eb[(long)g1 * HID_HALF + h8]);
        const uint4 f2 = *reinterpret_cast<const uint4*>(&eb[(long)g2 * HID_HALF + h8]);
        const uint4 f3 = *reinterpret_cast<const uint4*>(&eb[(long)g3 * HID_HALF + h8]);
        const uint4 f4 = *reinterpret_cast<const uint4*>(&eb[(long)g4 * HID_HALF + h8]);
        const uint4 f5 = *reinterpret_cast<const uint4*>(&eb[(long)g5 * HID_HALF + h8]);
        const uint4 f6 = *reinterpret_cast<const uint4*>(&eb[(long)g6 * HID_HALF + h8]);
        const uint4 f7 = *reinterpret_cast<const uint4*>(&eb[(long)g7 * HID_HALF + h8]);

        fma8(f0, v0, a0, a1);
        fma8(f1, v1, b0, b1);
        fma8(f2, v2, a0, a1);
        fma8(f3, v3, b0, b1);
        fma8(f4, v4, a0, a1);
        fma8(f5, v5, b0, b1);
        fma8(f6, v6, a0, a1);
        fma8(f7, v7, b0, b1);
    }
    // tail: 8 nnz at a time, predicated by clamped index + zeroed value
    for (; i < hi; i += 8) {
        const int  idx = i + oct;
        const bool ok  = idx < hi;
        const int   gg = ga[ok ? idx : lo];
        const float vv = ok ? xv[idx] : 0.f;
        const uint4 f  = *reinterpret_cast<const uint4*>(&eb[(long)gg * HID_HALF + h8]);
        fma8(f, vv, a0, a1);
    }

    a0.x += b0.x; a0.y += b0.y; a0.z += b0.z; a0.w += b0.w;
    a1.x += b1.x; a1.y += b1.y; a1.z += b1.z; a1.w += b1.w;

    // cross-oct reduction (octs hold disjoint nnz subsets of the row)
    a0.x += __shfl_xor(a0.x, 8); a0.x += __shfl_xor(a0.x, 16); a0.x += __shfl_xor(a0.x, 32);
    a0.y += __shfl_xor(a0.y, 8); a0.y += __shfl_xor(a0.y, 16); a0.y += __shfl_xor(a0.y, 32);
    a0.z += __shfl_xor(a0.z, 8); a0.z += __shfl_xor(a0.z, 16); a0.z += __shfl_xor(a0.z, 32);
    a0.w += __shfl_xor(a0.w, 8); a0.w += __shfl_xor(a0.w, 16); a0.w += __shfl_xor(a0.w, 32);
    a1.x += __shfl_xor(a1.x, 8); a1.x += __shfl_xor(a1.x, 16); a1.x += __shfl_xor(a1.x, 32);
    a1.y += __shfl_xor(a1.y, 8); a1.y += __shfl_xor(a1.y, 16); a1.y += __shfl_xor(a1.y, 32);
    a1.z += __shfl_xor(a1.z, 8); a1.z += __shfl_xor(a1.z, 16); a1.z += __shfl_xor(a1.z, 32);
    a1.w += __shfl_xor(a1.w, 8); a1.w += __shfl_xor(a1.w, 16); a1.w += __shfl_xor(a1.w, 32);

    if (oct == 0) {
        float* o = &out[(long)r * NUM_HID + half * HID_HALF + h8];
        const vfloat4 s0 = { a0.x, a0.y, a0.z, a0.w };
        const vfloat4 s1 = { a1.x, a1.y, a1.z, a1.w };
        __builtin_nontemporal_store(s0, reinterpret_cast<vfloat4*>(o));
        __builtin_nontemporal_store(s1, reinterpret_cast<vfloat4*>(o + 4));
    }
}

// ---------------------------------------------------------------------------
// Fallback (ws too small): fp32, one wave per row, inline binary search.
// ---------------------------------------------------------------------------
__global__ __launch_bounds__(256) void omics_fp32_row_kernel(
    const float* __restrict__ xv, const int* __restrict__ xr,
    const int* __restrict__ xc, const int* __restrict__ gidx,
    const float* __restrict__ embs, float* __restrict__ out)
{
    const int wave = (blockIdx.x * blockDim.x + threadIdx.x) >> 6;
    const int lane = threadIdx.x & 63;
    if (wave >= N_CELLS) return;
    int lo = 0, hi = NNZ_TOT;
    while (lo < hi) { int m = (lo + hi) >> 1; if (xr[m] < wave) lo = m + 1; else hi = m; }
    int lo2 = lo, hi2 = NNZ_TOT;
    while (lo2 < hi2) { int m = (lo2 + hi2) >> 1; if (xr[m] < wave + 1) lo2 = m + 1; else hi2 = m; }
    const int h = lane * 2;
    float2 acc = make_float2(0.f, 0.f);
    for (int i = lo; i < lo2; ++i) {
        const float v = xv[i];
        const int   g = gidx[xc[i]];
        const float2 f = *reinterpret_cast<const float2*>(&embs[(long)g * NUM_HID + h]);
        acc.x = fmaf(v, f.x, acc.x);
        acc.y = fmaf(v, f.y, acc.y);
    }
    *reinterpret_cast<float2*>(&out[(long)wave * NUM_HID + h]) = acc;
}

extern "C" void kernel_launch(void* const* d_in, const int* in_sizes, int n_in,
                              void* d_out, int out_size, void* d_ws, size_t ws_size,
                              hipStream_t stream) {
    const float* xv   = (const float*)d_in[0];
    const int*   xr   = (const int*)  d_in[1];
    const int*   xc   = (const int*)  d_in[2];
    const int*   gidx = (const int*)  d_in[3];
    const float* embs = (const float*)d_in[4];
    float*       out  = (float*)d_out;

    if (ws_size >= WS_NEED) {
        int*            ga   = (int*)((char*)d_ws + GA_OFF);
        unsigned short* ebf0 = (unsigned short*)((char*)d_ws + EBF0_OFF);
        unsigned short* ebf1 = (unsigned short*)((char*)d_ws + EBF1_OFF);
        int*            rp   = (int*)((char*)d_ws + RP_OFF);

        precompute_kernel<<<NB_GA + NB_RP, 256, 0, stream>>>(xc, gidx, xr, ga, rp);
        convert_embs_kernel<<<(N_PRE * NUM_HID / 4 + 255) / 256, 256, 0, stream>>>(
            embs, ebf0, ebf1);

        omics_half_kernel<<<(N_CELLS / 4) * 2, 256, 0, stream>>>(
            xv, ga, rp, ebf0, ebf1, out);
    } else {
        omics_fp32_row_kernel<<<(N_CELLS * 64) / 256, 256, 0, stream>>>(
            xv, xr, xc, gidx, embs, out);
    }
}

// Round 6
// 141.857 us; speedup vs baseline: 1.0150x; 1.0150x over previous
//
#include <hip/hip_runtime.h>

// Problem constants (from reference)
#define NNZ_TOT    2097152
#define N_CELLS    4096
#define N_GIN      20000     // input genes
#define N_PRE      30000     // pretrained table rows
#define NUM_HID    128

// Workspace: g_arr [NNZ] int, e8 [N_PRE,128] uint8 (biased int8, global
// scale), rp [N_CELLS+1] int, sc (global maxabs, 1 float)
#define GA_OFF    0
#define GA_BYTES  ((size_t)NNZ_TOT * 4)                       // 8 MB
#define E8_OFF    (GA_OFF + GA_BYTES)
#define E8_BYTES  ((size_t)N_PRE * NUM_HID)                   // 3.84 MB
#define RP_OFF    (E8_OFF + E8_BYTES)
#define RP_BYTES  ((((size_t)(N_CELLS + 1) * 4) + 255) & ~(size_t)255)
#define SC_OFF    (RP_OFF + RP_BYTES)
#define SC_BYTES  256
#define WS_NEED   (SC_OFF + SC_BYTES)

// ---------------------------------------------------------------------------
// P1: fused precompute — three block segments:
//   [0, NB_GA): g_arr[i] = gidx[xc[i]]
//   [NB_GA, NB_GA+NB_RP): CSR row pointers (binary search)
//   [NB_GA+NB_RP, +NB_MX): grid-stride max|embs| -> atomicMax into sc
//     (sc is memset to 0 in kernel_launch first; ws is harness-poisoned)
// ---------------------------------------------------------------------------
#define NB_GA ((NNZ_TOT + 255) / 256)         // 8192 blocks
#define NB_RP ((N_CELLS + 256) / 256)         // 17 blocks
#define NB_MX 512

__global__ __launch_bounds__(256) void precompute_kernel(
    const int* __restrict__ xc, const int* __restrict__ gidx,
    const int* __restrict__ xr, const float* __restrict__ embs,
    int* __restrict__ g_arr, int* __restrict__ rp,
    unsigned int* __restrict__ sc)
{
    const int b = blockIdx.x;
    if (b < NB_GA) {
        const int i = b * 256 + threadIdx.x;
        if (i < NNZ_TOT) g_arr[i] = gidx[xc[i]];
    } else if (b < NB_GA + NB_RP) {
        const int r = (b - NB_GA) * 256 + threadIdx.x;
        if (r <= N_CELLS) {
            int lo = 0, hi = NNZ_TOT;
            while (lo < hi) {
                const int mid = (lo + hi) >> 1;
                if (xr[mid] < r) lo = mid + 1; else hi = mid;
            }
            rp[r] = lo;
        }
    } else {
        const int t = (b - NB_GA - NB_RP) * 256 + (int)threadIdx.x;
        const float4* __restrict__ e4 = reinterpret_cast<const float4*>(embs);
        float m = 0.f;
        for (int j = t; j < N_PRE * NUM_HID / 4; j += NB_MX * 256) {
            const float4 f = e4[j];
            m = fmaxf(m, fmaxf(fmaxf(fabsf(f.x), fabsf(f.y)),
                               fmaxf(fabsf(f.z), fabsf(f.w))));
        }
        for (int d = 1; d < 64; d <<= 1) m = fmaxf(m, __shfl_xor(m, d));
        if ((threadIdx.x & 63) == 0) atomicMax(sc, __float_as_uint(m));
    }
}

// ---------------------------------------------------------------------------
// P2: int8 copy of the embedding table (rows 512 B -> 128 B), biased-uint8
// with ONE global scale = maxabs/127. Uniform ABSOLUTE step (~2.2e-4) beats
// fp8 e4m3's relative step (which hit 2e-3 on the largest entries -> R4's
// 8.4e-3 absmax fail). Predicted accumulated absmax ~4e-3 < 6.48e-3 thr.
// Halves the bf16 gather volume: 2M nnz x 128 B = 256 MB.
// ---------------------------------------------------------------------------
__global__ __launch_bounds__(256) void convert_embs8_kernel(
    const float* __restrict__ embs, const unsigned int* __restrict__ sc,
    unsigned int* __restrict__ e8)
{
    const int i = blockIdx.x * blockDim.x + threadIdx.x;   // one dword = 4 elems
    const long idx = (long)i * 4;
    if (idx < (long)N_PRE * NUM_HID) {
        const float maxabs = __uint_as_float(*sc);
        const float s = (maxabs > 0.f) ? 127.0f / maxabs : 0.f;
        const float4 f = *reinterpret_cast<const float4*>(&embs[idx]);
        int b0 = (int)rintf(f.x * s) + 128;
        int b1 = (int)rintf(f.y * s) + 128;
        int b2 = (int)rintf(f.z * s) + 128;
        int b3 = (int)rintf(f.w * s) + 128;
        b0 = min(max(b0, 0), 255); b1 = min(max(b1, 0), 255);
        b2 = min(max(b2, 0), 255); b3 = min(max(b3, 0), 255);
        e8[i] = (unsigned)b0 | ((unsigned)b1 << 8) |
                ((unsigned)b2 << 16) | ((unsigned)b3 << 24);
    }
}

// ---------------------------------------------------------------------------
// Main: one wave per output row; zero atomics; 2-hop chains (ga -> e8).
// int8 rows are 128 B: lane = (oct = lane>>3 picks 1 of 8 consecutive nnz,
// sub = lane&7 owns dims [sub*16, sub*16+16)) -> one global_load_dwordx4
// fetches 8 complete 128-B rows, every fetched byte consumed. 64 nnz/iter =
// 8 independent gather chains. Decode: (float)((w>>8k)&0xff) — LLVM folds
// this to v_cvt_f32_ubyte0..3 (1 VALU/dim); the -128 bias is hoisted:
// out_d = scale*(B_d - 128*S), S = sum(v).
// Plain loads (R10: nt harmful; R1: nt+split regressed). Measured
// invariants: gather service ~19 B/cyc/CU @256-B runs, ~16.5 @128-B runs,
// structure- and fill-source-insensitive -> only bytes matter. 256 MB here.
// ---------------------------------------------------------------------------
#define U2F0(w) ((float)((w) & 0xffu))
#define U2F1(w) ((float)(((w) >> 8)  & 0xffu))
#define U2F2(w) ((float)(((w) >> 16) & 0xffu))
#define U2F3(w) ((float)(((w) >> 24) & 0xffu))

__device__ __forceinline__ void fma16i(uint4 f, float vv,
                                       float4& a0, float4& a1,
                                       float4& a2, float4& a3, float& S) {
    a0.x = fmaf(vv, U2F0(f.x), a0.x);
    a0.y = fmaf(vv, U2F1(f.x), a0.y);
    a0.z = fmaf(vv, U2F2(f.x), a0.z);
    a0.w = fmaf(vv, U2F3(f.x), a0.w);
    a1.x = fmaf(vv, U2F0(f.y), a1.x);
    a1.y = fmaf(vv, U2F1(f.y), a1.y);
    a1.z = fmaf(vv, U2F2(f.y), a1.z);
    a1.w = fmaf(vv, U2F3(f.y), a1.w);
    a2.x = fmaf(vv, U2F0(f.z), a2.x);
    a2.y = fmaf(vv, U2F1(f.z), a2.y);
    a2.z = fmaf(vv, U2F2(f.z), a2.z);
    a2.w = fmaf(vv, U2F3(f.z), a2.w);
    a3.x = fmaf(vv, U2F0(f.w), a3.x);
    a3.y = fmaf(vv, U2F1(f.w), a3.y);
    a3.z = fmaf(vv, U2F2(f.w), a3.z);
    a3.w = fmaf(vv, U2F3(f.w), a3.w);
    S += vv;
}

__global__ __launch_bounds__(256) void omics_row8_kernel(
    const float*        __restrict__ xv,    // [NNZ] values
    const int*          __restrict__ ga,    // [NNZ] gene ids (fused)
    const int*          __restrict__ rp,    // [N_CELLS+1]
    const unsigned int* __restrict__ e8,    // [N_PRE,128] u8 as dwords
    const unsigned int* __restrict__ sc,    // global maxabs
    float*              __restrict__ out)   // [N_CELLS,128]
{
    const int wave = (blockIdx.x * blockDim.x + threadIdx.x) >> 6;
    const int lane = threadIdx.x & 63;
    const int sub  = lane & 7;              // 16-dim chunk within the row
    const int oct  = lane >> 3;             // 1 of 8 consecutive nnz
    const int r    = __builtin_amdgcn_readfirstlane(wave);
    if (r >= N_CELLS) return;

    const uint4* __restrict__ ebq = reinterpret_cast<const uint4*>(e8);
    // row g occupies uint4 indices [g*8, g*8+8); this lane reads g*8+sub.

    const int lo = rp[r];
    const int hi = rp[r + 1];

    float4 a0 = make_float4(0.f,0.f,0.f,0.f), a1 = a0, a2 = a0, a3 = a0;
    float4 b0 = a0, b1 = a0, b2 = a0, b3 = a0;
    float Sa = 0.f, Sb = 0.f;

    int i = lo;
    for (; i + 64 <= hi; i += 64) {
        const int i0 = i + oct;
        const int g0 = ga[i0];      const float v0 = xv[i0];
        const int g1 = ga[i0 + 8];  const float v1 = xv[i0 + 8];
        const int g2 = ga[i0 + 16]; const float v2 = xv[i0 + 16];
        const int g3 = ga[i0 + 24]; const float v3 = xv[i0 + 24];
        const int g4 = ga[i0 + 32]; const float v4 = xv[i0 + 32];
        const int g5 = ga[i0 + 40]; const float v5 = xv[i0 + 40];
        const int g6 = ga[i0 + 48]; const float v6 = xv[i0 + 48];
        const int g7 = ga[i0 + 56]; const float v7 = xv[i0 + 56];

        const uint4 f0 = ebq[(long)g0 * 8 + sub];
        const uint4 f1 = ebq[(long)g1 * 8 + sub];
        const uint4 f2 = ebq[(long)g2 * 8 + sub];
        const uint4 f3 = ebq[(long)g3 * 8 + sub];
        const uint4 f4 = ebq[(long)g4 * 8 + sub];
        const uint4 f5 = ebq[(long)g5 * 8 + sub];
        const uint4 f6 = ebq[(long)g6 * 8 + sub];
        const uint4 f7 = ebq[(long)g7 * 8 + sub];

        fma16i(f0, v0, a0, a1, a2, a3, Sa);
        fma16i(f1, v1, b0, b1, b2, b3, Sb);
        fma16i(f2, v2, a0, a1, a2, a3, Sa);
        fma16i(f3, v3, b0, b1, b2, b3, Sb);
        fma16i(f4, v4, a0, a1, a2, a3, Sa);
        fma16i(f5, v5, b0, b1, b2, b3, Sb);
        fma16i(f6, v6, a0, a1, a2, a3, Sa);
        fma16i(f7, v7, b0, b1, b2, b3, Sb);
    }
    // tail: 8 nnz at a time, predicated by clamped index + zeroed value
    for (; i < hi; i += 8) {
        const int  idx = i + oct;
        const bool ok  = idx < hi;
        const int   gg = ga[ok ? idx : lo];
        const float vv = ok ? xv[idx] : 0.f;
        const uint4 f  = ebq[(long)gg * 8 + sub];
        fma16i(f, vv, a0, a1, a2, a3, Sa);
    }

    a0.x += b0.x; a0.y += b0.y; a0.z += b0.z; a0.w += b0.w;
    a1.x += b1.x; a1.y += b1.y; a1.z += b1.z; a1.w += b1.w;
    a2.x += b2.x; a2.y += b2.y; a2.z += b2.z; a2.w += b2.w;
    a3.x += b3.x; a3.y += b3.y; a3.z += b3.z; a3.w += b3.w;
    Sa += Sb;

    // cross-oct reduction (octs hold disjoint nnz subsets of the row):
    // oct index lives in lane bits 3,4,5 -> xor distances 8,16,32.
    #define RED(c) c += __shfl_xor(c, 8); c += __shfl_xor(c, 16); c += __shfl_xor(c, 32)
    RED(a0.x); RED(a0.y); RED(a0.z); RED(a0.w);
    RED(a1.x); RED(a1.y); RED(a1.z); RED(a1.w);
    RED(a2.x); RED(a2.y); RED(a2.z); RED(a2.w);
    RED(a3.x); RED(a3.y); RED(a3.z); RED(a3.w);
    RED(Sa);
    #undef RED

    if (oct == 0) {
        const float maxabs = __uint_as_float(*sc);
        const float sdec   = (maxabs > 0.f) ? maxabs / 127.0f : 0.f;
        const float c      = 128.0f * Sa;   // bias correction, same all dims
        float* o = &out[(long)r * NUM_HID + sub * 16];
        *reinterpret_cast<float4*>(o)      = make_float4(
            sdec*(a0.x-c), sdec*(a0.y-c), sdec*(a0.z-c), sdec*(a0.w-c));
        *reinterpret_cast<float4*>(o + 4)  = make_float4(
            sdec*(a1.x-c), sdec*(a1.y-c), sdec*(a1.z-c), sdec*(a1.w-c));
        *reinterpret_cast<float4*>(o + 8)  = make_float4(
            sdec*(a2.x-c), sdec*(a2.y-c), sdec*(a2.z-c), sdec*(a2.w-c));
        *reinterpret_cast<float4*>(o + 12) = make_float4(
            sdec*(a3.x-c), sdec*(a3.y-c), sdec*(a3.z-c), sdec*(a3.w-c));
    }
}

// ---------------------------------------------------------------------------
// Fallback (ws too small): fp32, one wave per row, inline binary search.
// ---------------------------------------------------------------------------
__global__ __launch_bounds__(256) void omics_fp32_row_kernel(
    const float* __restrict__ xv, const int* __restrict__ xr,
    const int* __restrict__ xc, const int* __restrict__ gidx,
    const float* __restrict__ embs, float* __restrict__ out)
{
    const int wave = (blockIdx.x * blockDim.x + threadIdx.x) >> 6;
    const int lane = threadIdx.x & 63;
    if (wave >= N_CELLS) return;
    int lo = 0, hi = NNZ_TOT;
    while (lo < hi) { int m = (lo + hi) >> 1; if (xr[m] < wave) lo = m + 1; else hi = m; }
    int lo2 = lo, hi2 = NNZ_TOT;
    while (lo2 < hi2) { int m = (lo2 + hi2) >> 1; if (xr[m] < wave + 1) lo2 = m + 1; else hi2 = m; }
    const int h = lane * 2;
    float2 acc = make_float2(0.f, 0.f);
    for (int i = lo; i < lo2; ++i) {
        const float v = xv[i];
        const int   g = gidx[xc[i]];
        const float2 f = *reinterpret_cast<const float2*>(&embs[(long)g * NUM_HID + h]);
        acc.x = fmaf(v, f.x, acc.x);
        acc.y = fmaf(v, f.y, acc.y);
    }
    *reinterpret_cast<float2*>(&out[(long)wave * NUM_HID + h]) = acc;
}

extern "C" void kernel_launch(void* const* d_in, const int* in_sizes, int n_in,
                              void* d_out, int out_size, void* d_ws, size_t ws_size,
                              hipStream_t stream) {
    const float* xv   = (const float*)d_in[0];
    const int*   xr   = (const int*)  d_in[1];
    const int*   xc   = (const int*)  d_in[2];
    const int*   gidx = (const int*)  d_in[3];
    const float* embs = (const float*)d_in[4];
    float*       out  = (float*)d_out;

    if (ws_size >= WS_NEED) {
        int*          ga = (int*)((char*)d_ws + GA_OFF);
        unsigned int* e8 = (unsigned int*)((char*)d_ws + E8_OFF);
        int*          rp = (int*)((char*)d_ws + RP_OFF);
        unsigned int* sc = (unsigned int*)((char*)d_ws + SC_OFF);

        // ws is harness-poisoned each iteration; atomicMax needs a zero slot.
        (void)hipMemsetAsync(sc, 0, 4, stream);

        precompute_kernel<<<NB_GA + NB_RP + NB_MX, 256, 0, stream>>>(
            xc, gidx, xr, embs, ga, rp, sc);
        convert_embs8_kernel<<<(N_PRE * NUM_HID / 4 + 255) / 256, 256, 0, stream>>>(
            embs, sc, e8);

        omics_row8_kernel<<<(N_CELLS * 64) / 256, 256, 0, stream>>>(
            xv, ga, rp, e8, sc, out);
    } else {
        omics_fp32_row_kernel<<<(N_CELLS * 64) / 256, 256, 0, stream>>>(
            xv, xr, xc, gidx, embs, out);
    }
}

// Round 7
// 123.442 us; speedup vs baseline: 1.1664x; 1.1492x over previous
//
#include <hip/hip_runtime.h>

// Problem constants (from reference)
#define NNZ_TOT    2097152
#define N_CELLS    4096
#define N_GIN      20000     // input genes
#define N_PRE      30000     // pretrained table rows
#define NUM_HID    128

// Workspace: ga [NNZ] u16, e8 [N_PRE,128] u8 (biased int8, PER-ROW step),
// rs [N_PRE] f32 (row step = rowmax/127), rp [N_CELLS+1] int
#define GA_OFF    0
#define GA_BYTES  ((((size_t)NNZ_TOT * 2) + 255) & ~(size_t)255)   // 4 MB
#define E8_OFF    (GA_OFF + GA_BYTES)
#define E8_BYTES  ((size_t)N_PRE * NUM_HID)                        // 3.84 MB
#define RS_OFF    (E8_OFF + E8_BYTES)
#define RS_BYTES  ((((size_t)N_PRE * 4) + 255) & ~(size_t)255)     // 120 KB
#define RP_OFF    (RS_OFF + RS_BYTES)
#define RP_BYTES  ((((size_t)(N_CELLS + 1) * 4) + 255) & ~(size_t)255)
#define WS_NEED   (RP_OFF + RP_BYTES)

// ---------------------------------------------------------------------------
// P1: fused precompute — two block segments (maxabs segment REMOVED; its
// 512-block straggler tail ran at 2 blocks/CU with dependent strided loads
// and is the prime suspect for R6's +6us total regression):
//   [0, NB_GA): ga[i] = (u16)gidx[xc[i]]   (gene ids < 30000 fit u16)
//   [NB_GA, NB_GA+NB_RP): CSR row pointers (binary search)
// ---------------------------------------------------------------------------
#define NB_GA ((NNZ_TOT + 255) / 256)         // 8192 blocks
#define NB_RP ((N_CELLS + 256) / 256)         // 17 blocks

__global__ __launch_bounds__(256) void precompute_kernel(
    const int* __restrict__ xc, const int* __restrict__ gidx,
    const int* __restrict__ xr, unsigned short* __restrict__ ga,
    int* __restrict__ rp)
{
    const int b = blockIdx.x;
    if (b < NB_GA) {
        const int i = b * 256 + threadIdx.x;
        if (i < NNZ_TOT) ga[i] = (unsigned short)gidx[xc[i]];
    } else {
        const int r = (b - NB_GA) * 256 + threadIdx.x;
        if (r <= N_CELLS) {
            int lo = 0, hi = NNZ_TOT;
            while (lo < hi) {
                const int mid = (lo + hi) >> 1;
                if (xr[mid] < r) lo = mid + 1; else hi = mid;
            }
            rp[r] = lo;
        }
    }
}

// ---------------------------------------------------------------------------
// P2: int8 table with PER-ROW scale, fully self-contained (no global max,
// no memset, no serial scale dependency). One wave per row: coalesced load
// of 128 floats, 6-shfl max-reduce, quantize b = rint(e/step)+128 with
// step = rowmax/127, byte-store (64 consecutive bytes/instr = coalesced),
// store step in rs[row]. Per-row step ~1.1e-4 beats R6's global 2.0e-4 ->
// predicted absmax ~3e-3 (R6 measured 3.9e-3 with global scale).
// Rows 512 B -> 128 B: halves bf16 gather volume; 2M nnz x 128 B = 256 MB.
// ---------------------------------------------------------------------------
__global__ __launch_bounds__(256) void convert_embs8_kernel(
    const float* __restrict__ embs, unsigned char* __restrict__ e8,
    float* __restrict__ rs)
{
    const int row  = (blockIdx.x * blockDim.x + threadIdx.x) >> 6;
    const int lane = threadIdx.x & 63;
    if (row >= N_PRE) return;
    const long base = (long)row * NUM_HID;
    const float e0 = embs[base + lane];
    const float e1 = embs[base + 64 + lane];
    float m = fmaxf(fabsf(e0), fabsf(e1));
    for (int d = 1; d < 64; d <<= 1) m = fmaxf(m, __shfl_xor(m, d));
    const float sinv = (m > 0.f) ? 127.0f / m : 0.f;
    int b0 = (int)rintf(e0 * sinv) + 128;
    int b1 = (int)rintf(e1 * sinv) + 128;
    b0 = min(max(b0, 0), 255);
    b1 = min(max(b1, 0), 255);
    e8[base + lane]      = (unsigned char)b0;
    e8[base + 64 + lane] = (unsigned char)b1;
    if (lane == 0) rs[row] = m * (1.0f / 127.0f);
}

// ---------------------------------------------------------------------------
// Main: one wave per output row; zero atomics; 2-hop chains (ga -> e8).
// int8 rows are 128 B: lane = (oct = lane>>3 picks 1 of 8 consecutive nnz,
// sub = lane&7 owns dims [sub*16, sub*16+16)) -> one global_load_dwordx4
// fetches 8 complete 128-B rows, every fetched byte consumed. 64 nnz/iter =
// 8 independent gather chains. Decode: (float)((w>>8k)&0xff) — LLVM folds
// to v_cvt_f32_ubyte0..3 (1 VALU/dim). Per-row step folds into the value:
// w = v * rs[g] (rs is 120 KB, L1/L2-hot); bias hoisted:
// out_d = A_d - 128*S,  A_d = sum w*b_d,  S = sum w.  No final descale.
// Plain loads (R10: nt harmful; R1: nt+split regressed). Measured
// invariants: gather service ~19 B/cyc/CU @256-B runs, ~16.5 @128-B runs,
// structure- and fill-source-insensitive -> only bytes matter. 256 MB here.
// ---------------------------------------------------------------------------
#define U2F0(w) ((float)((w) & 0xffu))
#define U2F1(w) ((float)(((w) >> 8)  & 0xffu))
#define U2F2(w) ((float)(((w) >> 16) & 0xffu))
#define U2F3(w) ((float)(((w) >> 24) & 0xffu))

__device__ __forceinline__ void fma16i(uint4 f, float vv,
                                       float4& a0, float4& a1,
                                       float4& a2, float4& a3, float& S) {
    a0.x = fmaf(vv, U2F0(f.x), a0.x);
    a0.y = fmaf(vv, U2F1(f.x), a0.y);
    a0.z = fmaf(vv, U2F2(f.x), a0.z);
    a0.w = fmaf(vv, U2F3(f.x), a0.w);
    a1.x = fmaf(vv, U2F0(f.y), a1.x);
    a1.y = fmaf(vv, U2F1(f.y), a1.y);
    a1.z = fmaf(vv, U2F2(f.y), a1.z);
    a1.w = fmaf(vv, U2F3(f.y), a1.w);
    a2.x = fmaf(vv, U2F0(f.z), a2.x);
    a2.y = fmaf(vv, U2F1(f.z), a2.y);
    a2.z = fmaf(vv, U2F2(f.z), a2.z);
    a2.w = fmaf(vv, U2F3(f.z), a2.w);
    a3.x = fmaf(vv, U2F0(f.w), a3.x);
    a3.y = fmaf(vv, U2F1(f.w), a3.y);
    a3.z = fmaf(vv, U2F2(f.w), a3.z);
    a3.w = fmaf(vv, U2F3(f.w), a3.w);
    S += vv;
}

__global__ __launch_bounds__(256) void omics_row8_kernel(
    const float*          __restrict__ xv,   // [NNZ] values
    const unsigned short* __restrict__ ga,   // [NNZ] gene ids (u16, fused)
    const int*            __restrict__ rp,   // [N_CELLS+1]
    const unsigned int*   __restrict__ e8,   // [N_PRE,128] u8 as dwords
    const float*          __restrict__ rs,   // [N_PRE] row step
    float*                __restrict__ out)  // [N_CELLS,128]
{
    const int wave = (blockIdx.x * blockDim.x + threadIdx.x) >> 6;
    const int lane = threadIdx.x & 63;
    const int sub  = lane & 7;              // 16-dim chunk within the row
    const int oct  = lane >> 3;             // 1 of 8 consecutive nnz
    const int r    = __builtin_amdgcn_readfirstlane(wave);
    if (r >= N_CELLS) return;

    const uint4* __restrict__ ebq = reinterpret_cast<const uint4*>(e8);
    // row g occupies uint4 indices [g*8, g*8+8); this lane reads g*8+sub.

    const int lo = rp[r];
    const int hi = rp[r + 1];

    float4 a0 = make_float4(0.f,0.f,0.f,0.f), a1 = a0, a2 = a0, a3 = a0;
    float4 b0 = a0, b1 = a0, b2 = a0, b3 = a0;
    float Sa = 0.f, Sb = 0.f;

    int i = lo;
    for (; i + 64 <= hi; i += 64) {
        const int i0 = i + oct;
        const int g0 = ga[i0];      const float w0 = xv[i0]      * rs[g0];
        const int g1 = ga[i0 + 8];  const float w1 = xv[i0 + 8]  * rs[g1];
        const int g2 = ga[i0 + 16]; const float w2 = xv[i0 + 16] * rs[g2];
        const int g3 = ga[i0 + 24]; const float w3 = xv[i0 + 24] * rs[g3];
        const int g4 = ga[i0 + 32]; const float w4 = xv[i0 + 32] * rs[g4];
        const int g5 = ga[i0 + 40]; const float w5 = xv[i0 + 40] * rs[g5];
        const int g6 = ga[i0 + 48]; const float w6 = xv[i0 + 48] * rs[g6];
        const int g7 = ga[i0 + 56]; const float w7 = xv[i0 + 56] * rs[g7];

        const uint4 f0 = ebq[(long)g0 * 8 + sub];
        const uint4 f1 = ebq[(long)g1 * 8 + sub];
        const uint4 f2 = ebq[(long)g2 * 8 + sub];
        const uint4 f3 = ebq[(long)g3 * 8 + sub];
        const uint4 f4 = ebq[(long)g4 * 8 + sub];
        const uint4 f5 = ebq[(long)g5 * 8 + sub];
        const uint4 f6 = ebq[(long)g6 * 8 + sub];
        const uint4 f7 = ebq[(long)g7 * 8 + sub];

        fma16i(f0, w0, a0, a1, a2, a3, Sa);
        fma16i(f1, w1, b0, b1, b2, b3, Sb);
        fma16i(f2, w2, a0, a1, a2, a3, Sa);
        fma16i(f3, w3, b0, b1, b2, b3, Sb);
        fma16i(f4, w4, a0, a1, a2, a3, Sa);
        fma16i(f5, w5, b0, b1, b2, b3, Sb);
        fma16i(f6, w6, a0, a1, a2, a3, Sa);
        fma16i(f7, w7, b0, b1, b2, b3, Sb);
    }
    // tail: 8 nnz at a time, predicated by clamped index + zeroed value
    for (; i < hi; i += 8) {
        const int  idx = i + oct;
        const bool ok  = idx < hi;
        const int   gg = ga[ok ? idx : lo];
        const float vv = ok ? xv[idx] * rs[gg] : 0.f;
        const uint4 f  = ebq[(long)gg * 8 + sub];
        fma16i(f, vv, a0, a1, a2, a3, Sa);
    }

    a0.x += b0.x; a0.y += b0.y; a0.z += b0.z; a0.w += b0.w;
    a1.x += b1.x; a1.y += b1.y; a1.z += b1.z; a1.w += b1.w;
    a2.x += b2.x; a2.y += b2.y; a2.z += b2.z; a2.w += b2.w;
    a3.x += b3.x; a3.y += b3.y; a3.z += b3.z; a3.w += b3.w;
    Sa += Sb;

    // cross-oct reduction (octs hold disjoint nnz subsets of the row):
    // oct index lives in lane bits 3,4,5 -> xor distances 8,16,32.
    #define RED(c) c += __shfl_xor(c, 8); c += __shfl_xor(c, 16); c += __shfl_xor(c, 32)
    RED(a0.x); RED(a0.y); RED(a0.z); RED(a0.w);
    RED(a1.x); RED(a1.y); RED(a1.z); RED(a1.w);
    RED(a2.x); RED(a2.y); RED(a2.z); RED(a2.w);
    RED(a3.x); RED(a3.y); RED(a3.z); RED(a3.w);
    RED(Sa);
    #undef RED

    if (oct == 0) {
        const float c = 128.0f * Sa;   // bias correction, same all dims
        float* o = &out[(long)r * NUM_HID + sub * 16];
        *reinterpret_cast<float4*>(o)      = make_float4(a0.x-c, a0.y-c, a0.z-c, a0.w-c);
        *reinterpret_cast<float4*>(o + 4)  = make_float4(a1.x-c, a1.y-c, a1.z-c, a1.w-c);
        *reinterpret_cast<float4*>(o + 8)  = make_float4(a2.x-c, a2.y-c, a2.z-c, a2.w-c);
        *reinterpret_cast<float4*>(o + 12) = make_float4(a3.x-c, a3.y-c, a3.z-c, a3.w-c);
    }
}

// ---------------------------------------------------------------------------
// Fallback (ws too small): fp32, one wave per row, inline binary search.
// ---------------------------------------------------------------------------
__global__ __launch_bounds__(256) void omics_fp32_row_kernel(
    const float* __restrict__ xv, const int* __restrict__ xr,
    const int* __restrict__ xc, const int* __restrict__ gidx,
    const float* __restrict__ embs, float* __restrict__ out)
{
    const int wave = (blockIdx.x * blockDim.x + threadIdx.x) >> 6;
    const int lane = threadIdx.x & 63;
    if (wave >= N_CELLS) return;
    int lo = 0, hi = NNZ_TOT;
    while (lo < hi) { int m = (lo + hi) >> 1; if (xr[m] < wave) lo = m + 1; else hi = m; }
    int lo2 = lo, hi2 = NNZ_TOT;
    while (lo2 < hi2) { int m = (lo2 + hi2) >> 1; if (xr[m] < wave + 1) lo2 = m + 1; else hi2 = m; }
    const int h = lane * 2;
    float2 acc = make_float2(0.f, 0.f);
    for (int i = lo; i < lo2; ++i) {
        const float v = xv[i];
        const int   g = gidx[xc[i]];
        const float2 f = *reinterpret_cast<const float2*>(&embs[(long)g * NUM_HID + h]);
        acc.x = fmaf(v, f.x, acc.x);
        acc.y = fmaf(v, f.y, acc.y);
    }
    *reinterpret_cast<float2*>(&out[(long)wave * NUM_HID + h]) = acc;
}

extern "C" void kernel_launch(void* const* d_in, const int* in_sizes, int n_in,
                              void* d_out, int out_size, void* d_ws, size_t ws_size,
                              hipStream_t stream) {
    const float* xv   = (const float*)d_in[0];
    const int*   xr   = (const int*)  d_in[1];
    const int*   xc   = (const int*)  d_in[2];
    const int*   gidx = (const int*)  d_in[3];
    const float* embs = (const float*)d_in[4];
    float*       out  = (float*)d_out;

    if (ws_size >= WS_NEED) {
        unsigned short* ga = (unsigned short*)((char*)d_ws + GA_OFF);
        unsigned char*  e8 = (unsigned char*)((char*)d_ws + E8_OFF);
        float*          rs = (float*)((char*)d_ws + RS_OFF);
        int*            rp = (int*)((char*)d_ws + RP_OFF);

        precompute_kernel<<<NB_GA + NB_RP, 256, 0, stream>>>(xc, gidx, xr, ga, rp);
        convert_embs8_kernel<<<(N_PRE * 64 + 255) / 256, 256, 0, stream>>>(
            embs, e8, rs);

        omics_row8_kernel<<<(N_CELLS * 64) / 256, 256, 0, stream>>>(
            xv, ga, rp, (const unsigned int*)e8, rs, out);
    } else {
        omics_fp32_row_kernel<<<(N_CELLS * 64) / 256, 256, 0, stream>>>(
            xv, xr, xc, gidx, embs, out);
    }
}